// Round 14
// baseline (192.925 us; speedup 1.0000x reference)
//
#include <hip/hip_runtime.h>
#include <math.h>

#define NPTS 4096
#define KNB  50
#define WGRID 64

// ---------------- device scratch (written every launch before read) ----------------
__device__ int   g_idx[NPTS * KNB];
__device__ float g_dt[NPTS * KNB * 2];
__device__ float g_nrm[NPTS * 3];
__device__ float g_t1[NPTS * 3];
__device__ float g_t2[NPTS * 3];
__device__ float g_bmin[NPTS * 2];
__device__ float g_ml[NPTS];

// ---------------- LAPACK-faithful helpers (fp32, branch-structure identical) -------
__device__ __forceinline__ float slapy2f(float x, float y) {
  float ax = fabsf(x), ay = fabsf(y);
  float w = fmaxf(ax, ay), z = fminf(ax, ay);
  if (z == 0.0f) return w;
  float t = z / w;
  return w * sqrtf(1.0f + t * t);
}

// LAPACK >= 3.10 slartg (c >= 0 convention)
__device__ __forceinline__ void slartgf(float f, float g, float* cs, float* sn, float* r) {
  const float safmin = 1.1754944e-38f;
  const float safmax = 8.5070592e+37f;
  const float rtmin = 1.0842022e-19f;
  const float rtmax = 6.5219496e+18f;
  if (g == 0.0f) {
    *cs = 1.0f; *sn = 0.0f; *r = f;
  } else if (f == 0.0f) {
    *cs = 0.0f; *sn = copysignf(1.0f, g); *r = fabsf(g);
  } else {
    float f1 = fabsf(f), g1 = fabsf(g);
    if (f1 > rtmin && f1 < rtmax && g1 > rtmin && g1 < rtmax) {
      float d = sqrtf(f * f + g * g);
      float p = 1.0f / d;
      *cs = f1 * p;
      *sn = g * copysignf(p, f);
      *r = copysignf(d, f);
    } else {
      float u = fminf(safmax, fmaxf(safmin, fmaxf(f1, g1)));
      float fs = f / u, gs = g / u;
      float d = sqrtf(fs * fs + gs * gs);
      float p = 1.0f / d;
      *cs = fabsf(fs) * p;
      *sn = gs * copysignf(p, f);
      *r = copysignf(d, f) * u;
    }
  }
}

__device__ void slaev2f(float a, float b, float c, float* rt1, float* rt2,
                        float* cs1, float* sn1) {
  float sm = a + c;
  float df = a - c;
  float adf = fabsf(df);
  float tb = b + b;
  float ab = fabsf(tb);
  float acmx, acmn;
  if (fabsf(a) > fabsf(c)) { acmx = a; acmn = c; } else { acmx = c; acmn = a; }
  float rt;
  if (adf > ab)      { float t = ab / adf; rt = adf * sqrtf(1.0f + t * t); }
  else if (adf < ab) { float t = adf / ab; rt = ab * sqrtf(1.0f + t * t); }
  else               { rt = ab * sqrtf(2.0f); }
  int sgn1;
  if (sm < 0.0f) {
    *rt1 = 0.5f * (sm - rt); sgn1 = -1;
    *rt2 = (acmx / *rt1) * acmn - (b / *rt1) * b;
  } else if (sm > 0.0f) {
    *rt1 = 0.5f * (sm + rt); sgn1 = 1;
    *rt2 = (acmx / *rt1) * acmn - (b / *rt1) * b;
  } else {
    *rt1 = 0.5f * rt; *rt2 = -0.5f * rt; sgn1 = 1;
  }
  float cs; int sgn2;
  if (df >= 0.0f) { cs = df + rt; sgn2 = 1; }
  else            { cs = df - rt; sgn2 = -1; }
  float acs = fabsf(cs);
  if (acs > ab) {
    float ct = -tb / cs;
    *sn1 = 1.0f / sqrtf(1.0f + ct * ct);
    *cs1 = ct * (*sn1);
  } else {
    if (ab == 0.0f) { *cs1 = 1.0f; *sn1 = 0.0f; }
    else {
      float tn = -cs / tb;
      *cs1 = 1.0f / sqrtf(1.0f + tn * tn);
      *sn1 = tn * (*cs1);
    }
  }
  if (sgn1 == sgn2) { float tn = *cs1; *cs1 = -(*sn1); *sn1 = tn; }
}

// ssteqr, n=3, COMPZ='I'.
__device__ void ssteqr3(float* d, float* e, float Z[3][3]) {
  const float eps = 5.9604645e-08f;
  const float eps2 = 3.5527137e-15f;
  const float safmin = 1.1754944e-38f;
  const float ssfmax = 3.0744574e+18f;
  const float ssfmin = 3.0517578e-05f;
  const int n = 3, nmaxit = 90;
  int jtot = 0;
  for (int r = 0; r < 3; ++r)
    for (int c = 0; c < 3; ++c) Z[r][c] = (r == c) ? 1.0f : 0.0f;

  int l1 = 1;
  while (l1 <= n) {
    if (l1 > 1) e[l1 - 2] = 0.0f;
    int m = n;
    for (int mm = l1; mm <= n - 1; ++mm) {
      float tst = fabsf(e[mm - 1]);
      if (tst == 0.0f) { m = mm; break; }
      if (tst <= (sqrtf(fabsf(d[mm - 1])) * sqrtf(fabsf(d[mm]))) * eps) {
        e[mm - 1] = 0.0f; m = mm; break;
      }
    }
    int l = l1, lsv = l1, lend = m, lendsv = m;
    l1 = m + 1;
    if (lend == l) continue;

    float anorm = 0.0f;
    for (int ii = l; ii <= lend; ++ii) anorm = fmaxf(anorm, fabsf(d[ii - 1]));
    for (int ii = l; ii <= lend - 1; ++ii) anorm = fmaxf(anorm, fabsf(e[ii - 1]));
    if (anorm == 0.0f) continue;
    int iscale = 0;
    if (anorm > ssfmax) {
      iscale = 1; float mul = ssfmax / anorm;
      for (int ii = l; ii <= lend; ++ii) d[ii - 1] *= mul;
      for (int ii = l; ii <= lend - 1; ++ii) e[ii - 1] *= mul;
    } else if (anorm < ssfmin) {
      iscale = 2; float mul = ssfmin / anorm;
      for (int ii = l; ii <= lend; ++ii) d[ii - 1] *= mul;
      for (int ii = l; ii <= lend - 1; ++ii) e[ii - 1] *= mul;
    }
    if (fabsf(d[lend - 1]) < fabsf(d[l - 1])) { lend = lsv; l = lendsv; }

    if (lend > l) {
      for (;;) {
        int mm = lend;
        if (l != lend) {
          for (int t = l; t <= lend - 1; ++t) {
            float tst = e[t - 1] * e[t - 1];
            if (tst <= (eps2 * fabsf(d[t - 1])) * fabsf(d[t]) + safmin) { mm = t; break; }
          }
        }
        if (mm < lend) e[mm - 1] = 0.0f;
        float p = d[l - 1];
        if (mm == l) {
          d[l - 1] = p; ++l;
          if (l <= lend) continue; break;
        }
        if (mm == l + 1) {
          float rt1, rt2, c, s;
          slaev2f(d[l - 1], e[l - 1], d[l], &rt1, &rt2, &c, &s);
          for (int r = 0; r < 3; ++r) {
            float t = Z[r][l];
            Z[r][l]     = c * t - s * Z[r][l - 1];
            Z[r][l - 1] = s * t + c * Z[r][l - 1];
          }
          d[l - 1] = rt1; d[l] = rt2; e[l - 1] = 0.0f;
          l += 2;
          if (l <= lend) continue; break;
        }
        if (jtot == nmaxit) break;
        ++jtot;
        float g = (d[l] - p) / (2.0f * e[l - 1]);
        float r = slapy2f(g, 1.0f);
        g = d[mm - 1] - p + e[l - 1] / (g + copysignf(r, g));
        float s = 1.0f, c = 1.0f;
        p = 0.0f;
        float cw[2], sw[2];
        for (int i = mm - 1; i >= l; --i) {
          float f = s * e[i - 1];
          float b = c * e[i - 1];
          slartgf(g, f, &c, &s, &r);
          if (i != mm - 1) e[i] = r;
          g = d[i] - p;
          r = (d[i - 1] - g) * s + 2.0f * c * b;
          p = s * r;
          d[i] = g + p;
          g = c * r - b;
          cw[i - l] = c; sw[i - l] = -s;
        }
        for (int j = mm - 1; j >= l; --j) {
          float cc = cw[j - l], ss = sw[j - l];
          for (int r2 = 0; r2 < 3; ++r2) {
            float t = Z[r2][j];
            Z[r2][j]     = cc * t - ss * Z[r2][j - 1];
            Z[r2][j - 1] = ss * t + cc * Z[r2][j - 1];
          }
        }
        d[l - 1] -= p;
        e[l - 1] = g;
      }
    } else {
      for (;;) {
        int mm = lend;
        if (l != lend) {
          for (int t = l; t >= lend + 1; --t) {
            float tst = e[t - 2] * e[t - 2];
            if (tst <= (eps2 * fabsf(d[t - 1])) * fabsf(d[t - 2]) + safmin) { mm = t; break; }
          }
        }
        if (mm > lend) e[mm - 2] = 0.0f;
        float p = d[l - 1];
        if (mm == l) {
          d[l - 1] = p; --l;
          if (l >= lend) continue; break;
        }
        if (mm == l - 1) {
          float rt1, rt2, c, s;
          slaev2f(d[l - 2], e[l - 2], d[l - 1], &rt1, &rt2, &c, &s);
          for (int r2 = 0; r2 < 3; ++r2) {
            float t = Z[r2][l - 1];
            Z[r2][l - 1] = c * t - s * Z[r2][l - 2];
            Z[r2][l - 2] = s * t + c * Z[r2][l - 2];
          }
          d[l - 2] = rt1; d[l - 1] = rt2; e[l - 2] = 0.0f;
          l -= 2;
          if (l >= lend) continue; break;
        }
        if (jtot == nmaxit) break;
        ++jtot;
        float g = (d[l - 2] - p) / (2.0f * e[l - 2]);
        float r = slapy2f(g, 1.0f);
        g = d[mm - 1] - p + e[l - 2] / (g + copysignf(r, g));
        float s = 1.0f, c = 1.0f;
        p = 0.0f;
        float cw[2], sw[2];
        for (int i = mm; i <= l - 1; ++i) {
          float f = s * e[i - 1];
          float b = c * e[i - 1];
          slartgf(g, f, &c, &s, &r);
          if (i != mm) e[i - 2] = r;
          g = d[i - 1] - p;
          r = (d[i] - g) * s + 2.0f * c * b;
          p = s * r;
          d[i - 1] = g + p;
          g = c * r - b;
          cw[i - mm] = c; sw[i - mm] = s;
        }
        for (int j = mm; j <= l - 1; ++j) {
          float cc = cw[j - mm], ss = sw[j - mm];
          for (int r2 = 0; r2 < 3; ++r2) {
            float t = Z[r2][j];
            Z[r2][j]     = cc * t - ss * Z[r2][j - 1];
            Z[r2][j - 1] = ss * t + cc * Z[r2][j - 1];
          }
        }
        d[l - 1] -= p;
        e[l - 2] = g;
      }
    }
    if (iscale == 1) {
      float mul = anorm / ssfmax;
      for (int ii = lsv; ii <= lendsv; ++ii) d[ii - 1] *= mul;
      for (int ii = lsv; ii <= lendsv - 1; ++ii) e[ii - 1] *= mul;
    } else if (iscale == 2) {
      float mul = anorm / ssfmin;
      for (int ii = lsv; ii <= lendsv; ++ii) d[ii - 1] *= mul;
      for (int ii = lsv; ii <= lendsv - 1; ++ii) e[ii - 1] *= mul;
    }
    if (jtot >= nmaxit) break;
  }
  for (int ii = 2; ii <= n; ++ii) {
    int i0 = ii - 1, k0 = i0;
    float p = d[i0 - 1];
    for (int j = ii; j <= n; ++j)
      if (d[j - 1] < p) { k0 = j; p = d[j - 1]; }
    if (k0 != i0) {
      d[k0 - 1] = d[i0 - 1]; d[i0 - 1] = p;
      for (int r2 = 0; r2 < 3; ++r2) {
        float t = Z[r2][i0 - 1]; Z[r2][i0 - 1] = Z[r2][k0 - 1]; Z[r2][k0 - 1] = t;
      }
    }
  }
}

__device__ void ssytrd3(float a11, float a21, float a31, float a22, float a32, float a33,
                        float d[3], float e[2], float* tau, float* u) {
  float xnorm = fabsf(a31);
  if (xnorm == 0.0f) {
    *tau = 0.0f; *u = 0.0f;
    d[0] = a11; d[1] = a22; d[2] = a33; e[0] = a21; e[1] = a32;
    return;
  }
  float beta = -copysignf(slapy2f(a21, xnorm), a21);
  float taui = (beta - a21) / beta;
  float uu = a31 * (1.0f / (a21 - beta));
  float w1 = taui * a22 + taui * (a32 * uu);
  float w2 = taui * a32 + (taui * uu) * a33;
  float alpha = -0.5f * taui * (w1 + w2 * uu);
  w1 += alpha; w2 += alpha * uu;
  float na22 = a22 - 2.0f * w1;
  float na32 = a32 - (uu * w1 + w2);
  float na33 = a33 - 2.0f * (uu * w2);
  d[0] = a11; d[1] = na22; d[2] = na33;
  e[0] = beta; e[1] = na32;
  *tau = taui; *u = uu;
}

// ---------------- K1: kNN via 2x8-bit radix-select (R12 exact code) ----------------
__global__ __launch_bounds__(256) void knn_kernel(const float* __restrict__ pts,
                                                  float* __restrict__ out, int N) {
  __shared__ unsigned skey[NPTS];      // 16 KB
  __shared__ unsigned hist[256];
  __shared__ unsigned sred[4];
  __shared__ unsigned sbin[2];
  __shared__ int   eqi[64];
  __shared__ float eqd[64];
  __shared__ unsigned eqn[1];
  const int i = blockIdx.x;
  const int tid = threadIdx.x;
  const int lane = tid & 63, wid = tid >> 6;
  if (i == 0 && tid == 0) out[0] = 0.0f;        // voro_curv accumulates atomically
  const float xi = pts[3 * i], yi = pts[3 * i + 1], zi = pts[3 * i + 2];
  const float d2i = xi * xi + yi * yi + zi * zi;
  hist[tid] = 0;
  if (tid == 0) eqn[0] = 0;
  __syncthreads();
  for (int j = tid; j < N; j += 256) {
    float xj = pts[3 * j], yj = pts[3 * j + 1], zj = pts[3 * j + 2];
    float d2j = xj * xj + yj * yj + zj * zj;
    float dot = fmaf(zi, zj, fmaf(yi, yj, xi * xj));
    float dist = (d2i - 2.0f * dot) + d2j;        // identical formula to R1..R13
    float dc = fminf(fmaxf(dist, 0.0f), 31.0f);
    unsigned u = (unsigned)(dc * 134217728.0f);   // *2^27 exact, trunc: monotone
    skey[j] = u;
    atomicAdd(&hist[u >> 24], 1u);                // fused pass-0 histogram
  }
  __syncthreads();
  unsigned prefix = 0, rank = 49;
  for (int pass = 0; pass < 2; ++pass) {
    const int shift = 24 - 8 * pass;
    if (pass) {
      for (int j = tid; j < N; j += 256) {
        unsigned u = skey[j];
        if ((u >> 24) == (prefix >> 24))
          atomicAdd(&hist[(u >> 16) & 255u], 1u);
      }
      __syncthreads();
    }
    unsigned h = hist[tid];
    unsigned c = h;
    #pragma unroll
    for (int off = 1; off < 64; off <<= 1) {
      unsigned o = __shfl_up(c, off);
      if (lane >= off) c += o;
    }
    if (lane == 63) sred[wid] = c;
    __syncthreads();
    unsigned wbase = 0;
    for (int w2 = 0; w2 < wid; ++w2) wbase += sred[w2];
    c += wbase;
    unsigned excl = c - h;
    if (rank >= excl && rank < c) { sbin[0] = (unsigned)tid; sbin[1] = rank - excl; }
    __syncthreads();
    prefix |= sbin[0] << shift;
    rank = sbin[1];
    __syncthreads();
    if (pass == 0) { hist[tid] = 0; __syncthreads(); }
  }
  const unsigned T = prefix;                      // low 16 bits zero
  int cnt = 0;
  for (int j = tid; j < N; j += 256) {
    unsigned u = skey[j];
    if (u < T && j != i) {
      ++cnt;
    } else if ((u & 0xFFFF0000u) == T) {
      float xj = pts[3 * j], yj = pts[3 * j + 1], zj = pts[3 * j + 2];
      float d2j = xj * xj + yj * yj + zj * zj;
      float dot = fmaf(zi, zj, fmaf(yi, yj, xi * xj));
      float dist = (d2i - 2.0f * dot) + d2j;
      unsigned e = atomicAdd(&eqn[0], 1u);
      if (e < 64u) { eqi[e] = j; eqd[e] = dist; }
    }
  }
  __syncthreads();
  unsigned cc = (unsigned)cnt;
  #pragma unroll
  for (int off = 1; off < 64; off <<= 1) {
    unsigned o = __shfl_up(cc, off);
    if (lane >= off) cc += o;
  }
  if (lane == 63) sred[wid] = cc;
  __syncthreads();
  unsigned wbase = 0;
  for (int w2 = 0; w2 < wid; ++w2) wbase += sred[w2];
  int base = 1 + (int)(wbase + cc - (unsigned)cnt);  // deterministic compaction slot
  for (int j = tid; j < N; j += 256) {
    unsigned u = skey[j];
    if (u < T && j != i) g_idx[i * KNB + (base++)] = j;
  }
  if (tid == 0) {
    g_idx[i * KNB] = i;                            // self = global min distance
    int slot = 1 + (int)(sred[0] + sred[1] + sred[2] + sred[3]);
    int need = KNB - slot;                         // >= 1
    int ne = (int)eqn[0]; if (ne > 64) ne = 64;
    for (int e2 = 0; e2 < need; ++e2) {            // exact (dist, index) ascending
      int bq = 0, bidx = 0x7FFFFFFF; float bd = 3.4e38f;
      for (int q = 0; q < ne; ++q) {
        if (eqi[q] < 0) continue;
        float dq = eqd[q];
        if (dq < bd || (dq == bd && eqi[q] < bidx)) { bd = dq; bidx = eqi[q]; bq = q; }
      }
      g_idx[i * KNB + slot + e2] = bidx;
      eqi[bq] = -1;
    }
  }
}

// ---------------- K2: frames, wave-per-point (exact R2 accumulation order) ---------
__global__ __launch_bounds__(256) void frames_kernel(const float* __restrict__ pts, int N) {
  __shared__ float sx[4][52], sy[4][52], sz[4][52];
  const int tid = threadIdx.x, lane = tid & 63, w = tid >> 6;
  const int i = blockIdx.x * 4 + w;
  const int base = i * KNB;
  if (lane < KNB) {
    int j = g_idx[base + lane];
    sx[w][lane] = pts[3 * j];
    sy[w][lane] = pts[3 * j + 1];
    sz[w][lane] = pts[3 * j + 2];
  }
  __syncthreads();
  float mx = 0.0f, my = 0.0f, mz = 0.0f;
  for (int kk = 0; kk < KNB; ++kk) { mx += sx[w][kk]; my += sy[w][kk]; mz += sz[w][kk]; }
  mx /= 50.0f; my /= 50.0f; mz /= 50.0f;
  float c00 = 0, c01 = 0, c02 = 0, c11 = 0, c12 = 0, c22 = 0;
  for (int kk = 0; kk < KNB; ++kk) {
    float cx = sx[w][kk] - mx, cy = sy[w][kk] - my, cz = sz[w][kk] - mz;
    c00 = fmaf(cx, cx, c00); c01 = fmaf(cx, cy, c01); c02 = fmaf(cx, cz, c02);
    c11 = fmaf(cy, cy, c11); c12 = fmaf(cy, cz, c12); c22 = fmaf(cz, cz, c22);
  }
  c00 *= 0.5f; c01 *= 0.5f; c02 *= 0.5f; c11 *= 0.5f; c12 *= 0.5f; c22 *= 0.5f;

  float d[3], e[2], tau, u;
  ssytrd3(c00, c01, c02, c11, c12, c22, d, e, &tau, &u);
  float Z[3][3];
  ssteqr3(d, e, Z);
  if (tau != 0.0f) {
    for (int c = 0; c < 3; ++c) {
      float sum = Z[1][c] + u * Z[2][c];
      Z[1][c] -= tau * sum;
      Z[2][c] -= tau * u * sum;
    }
  }
  float n0 = Z[0][0], n1 = Z[1][0], n2 = Z[2][0];
  float a0 = Z[0][1], a1 = Z[1][1], a2 = Z[2][1];
  float b0 = Z[0][2], b1 = Z[1][2], b2 = Z[2][2];
  float cxp = a1 * b2 - a2 * b1, cyp = a2 * b0 - a0 * b2, czp = a0 * b1 - a1 * b0;
  float det = n0 * cxp + n1 * cyp + n2 * czp;
  a0 *= det; a1 *= det; a2 *= det;

  const float xi = pts[3 * i], yi = pts[3 * i + 1], zi = pts[3 * i + 2];
  float dt0 = 0.0f, dt1 = 0.0f;
  float mn0 = 3.0e38f, mx0 = -3.0e38f, mn1 = 3.0e38f, mx1 = -3.0e38f;
  if (lane < KNB) {
    float dx = sx[w][lane] - xi, dy = sy[w][lane] - yi, dz = sz[w][lane] - zi;
    dt0 = dx * a0 + dy * a1 + dz * a2;
    dt1 = dx * b0 + dy * b1 + dz * b2;
    g_dt[2 * (base + lane)] = dt0;
    g_dt[2 * (base + lane) + 1] = dt1;
    mn0 = dt0; mx0 = dt0; mn1 = dt1; mx1 = dt1;
  }
  #pragma unroll
  for (int off = 32; off > 0; off >>= 1) {
    mn0 = fminf(mn0, __shfl_down(mn0, off));
    mx0 = fmaxf(mx0, __shfl_down(mx0, off));
    mn1 = fminf(mn1, __shfl_down(mn1, off));
    mx1 = fmaxf(mx1, __shfl_down(mx1, off));
  }
  if (lane == 0) {
    g_nrm[3 * i] = n0; g_nrm[3 * i + 1] = n1; g_nrm[3 * i + 2] = n2;
    g_t1[3 * i] = a0;  g_t1[3 * i + 1] = a1;  g_t1[3 * i + 2] = a2;
    g_t2[3 * i] = b0;  g_t2[3 * i + 1] = b1;  g_t2[3 * i + 2] = b2;
    float bmin0 = mn0 * 1.1f, bmax0 = mx0 * 1.1f;
    float bmin1 = mn1 * 1.1f, bmax1 = mx1 * 1.1f;
    float ml = fmaxf(bmax0 - bmin0, bmax1 - bmin1);
    g_bmin[2 * i] = bmin0; g_bmin[2 * i + 1] = bmin1;
    g_ml[i] = ml;
  }
}

// ---------------- K3: fused Voronoi (R12 pruning) + curv epilogue ------------------
// R8 lesson applied: the curv tail is register-light (slaev2f only, no ssteqr3) and
// the whole kernel is capped at 6 waves/EU with unroll-disabled loops, so the
// voronoi phase keeps its occupancy. va passes via LDS bit-identically; curv math
// and per-point accumulation order identical to R12's curv_kernel.
__global__ __launch_bounds__(256, 6) void voro_curv_kernel(float* __restrict__ out, int N) {
  __shared__ float2 sc[KNB];
  __shared__ float s0[52], s1[52], txs[52], tys[52], tzs[52];
  __shared__ int alist[64];
  __shared__ int acnt[1];
  __shared__ int swc[4];
  __shared__ float sva[1];
  const int i = blockIdx.x;
  const int tid = threadIdx.x;
  const int lane = tid & 63, wid = tid >> 6;   // 4 waves
  const float ml = g_ml[i];
  const float b0 = g_bmin[2 * i], b1 = g_bmin[2 * i + 1];
  if (tid < KNB) {
    int j = g_idx[i * KNB + tid];
    float dt0 = g_dt[2 * (i * KNB + tid)];
    float dt1 = g_dt[2 * (i * KNB + tid) + 1];
    sc[tid] = make_float2((dt0 - b0) / ml * 2.0f - 1.0f,
                          (dt1 - b1) / ml * 2.0f - 1.0f);
    s0[tid] = dt0; s1[tid] = dt1;              // curv inputs (raw dt)
    txs[tid] = g_nrm[3 * j];
    tys[tid] = g_nrm[3 * j + 1];
    tzs[tid] = g_nrm[3 * j + 2];
  }
  if (tid == 0) acnt[0] = 0;
  __syncthreads();
  const float step = 2.0f / 63.0f;
  // ---- stage 1: exact block-level pruning (thread tid < 64 owns grid-block tid) ---
  if (tid < 64) {
    const int bx = tid & 7, by = tid >> 3;
    const float gx0 = fmaf((float)(bx * 8), step, -1.0f);
    const float gx1 = fmaf((float)(bx * 8 + 7), step, -1.0f);
    const float gy0 = fmaf((float)(by * 8), step, -1.0f);
    const float gy1 = fmaf((float)(by * 8 + 7), step, -1.0f);
    const float s0x = sc[0].x, s0y = sc[0].y;
    const float n0s = s0x * s0x + s0y * s0y;
    bool dead = false;
    #pragma clang loop unroll(disable)
    for (int j = 1; j < KNB && !dead; ++j) {
      float sx = sc[j].x, sy = sc[j].y;
      float ax2 = 2.0f * (sx - s0x), ay2 = 2.0f * (sy - s0y);
      float cst = n0s - (sx * sx + sy * sy);
      float Lmin = fminf(ax2 * gx0, ax2 * gx1) + fminf(ay2 * gy0, ay2 * gy1) + cst;
      dead = Lmin > 1e-4f;                     // margin >> fp error: prune is exact
    }
    if (!dead) { int p = atomicAdd(&acnt[0], 1); alist[p] = tid; }
  }
  __syncthreads();
  const int na = acnt[0];
  // ---- stage 2: alive blocks only; per-cell math bit-identical to R1 --------------
  const float c0x = sc[0].x, c0y = sc[0].y;
  int cnt = 0;
  #pragma clang loop unroll(disable)
  for (int k = wid; k < na; k += 4) {
    int b = alist[k];
    int ix = (b & 7) * 8 + (lane & 7);
    int iy = (b >> 3) * 8 + (lane >> 3);
    float gx = fmaf((float)ix, step, -1.0f);
    float gy = fmaf((float)iy, step, -1.0f);
    float ex = gx - c0x, ey = gy - c0y;
    float d0 = ex * ex + ey * ey;              // same expr as R1
    float m = 3.0e38f;
    #pragma clang loop unroll(disable)
    for (int j = 1; j < KNB; ++j) {
      float dx = gx - sc[j].x, dy = gy - sc[j].y;
      float dd = fmaf(dx, dx, dy * dy);        // same expr as R1
      m = fminf(m, dd);                        // same fmin chain order (j asc)
    }
    cnt += (d0 <= m) ? 1 : 0;
  }
  #pragma unroll
  for (int off = 32; off > 0; off >>= 1) cnt += __shfl_down(cnt, off);
  if (lane == 0) swc[wid] = cnt;
  __syncthreads();
  if (tid == 0) {
    int tot = swc[0] + swc[1] + swc[2] + swc[3];
    sva[0] = (float)tot * (ml * ml) / 3969.0f;
  }
  __syncthreads();
  if (tid >= 64) return;                       // wave 0 only; lanes uniform
  // ---- fused curv (exact R12 accumulation order) ----
  float nx = g_nrm[3 * i], ny = g_nrm[3 * i + 1], nz = g_nrm[3 * i + 2];
  float ax = g_t1[3 * i], ay = g_t1[3 * i + 1], az = g_t1[3 * i + 2];
  float bx = g_t2[3 * i], by = g_t2[3 * i + 1], bz = g_t2[3 * i + 2];
  float xx = 0, xy = 0, yy = 0;
  float y00 = 0, y01 = 0, y10 = 0, y11 = 0;
  #pragma clang loop unroll(disable)
  for (int kk = 0; kk < KNB; ++kk) {
    float dt0 = s0[kk], dt1 = s1[kk];
    float lxv = txs[kk] - nx, lyv = tys[kk] - ny, lzv = tzs[kk] - nz;
    float dn0 = lxv * ax + lyv * ay + lzv * az;
    float dn1 = lxv * bx + lyv * by + lzv * bz;
    xx = fmaf(dt0, dt0, xx); xy = fmaf(dt0, dt1, xy); yy = fmaf(dt1, dt1, yy);
    y00 = fmaf(dn0, dt0, y00); y01 = fmaf(dn0, dt1, y01);
    y10 = fmaf(dn1, dt0, y10); y11 = fmaf(dn1, dt1, y11);
  }
  float s00 = y00 + y00, s01 = y01 + y10, s11 = y11 + y11;
  float rt1, rt2, cs1, sn1;
  slaev2f(xx, xy, yy, &rt1, &rt2, &cs1, &sn1);
  float a, bb, q00, q10, q01, q11;
  if (rt1 <= rt2) { a = rt1; bb = rt2; q00 = cs1; q10 = sn1; q01 = -sn1; q11 = cs1; }
  else            { a = rt2; bb = rt1; q00 = -sn1; q10 = cs1; q01 = cs1; q11 = sn1; }
  float t00 = s00 * q00 + s01 * q10, t01 = s00 * q01 + s01 * q11;
  float t10 = s01 * q00 + s11 * q10, t11 = s01 * q01 + s11 * q11;
  float m00 = q00 * t00 + q10 * t10;
  float m01v = q00 * t01 + q10 * t11;
  float m10 = q01 * t00 + q11 * t10;
  float m11 = q01 * t01 + q11 * t11;
  float e00 = m00 / (2.0f * a + 1e-8f);
  float e01 = m01v / ((a + bb) + 1e-8f);
  float e10 = m10 / ((a + bb) + 1e-8f);
  float e11 = m11 / (2.0f * bb + 1e-8f);
  float u00 = q00 * e00 + q01 * e10, u01 = q00 * e01 + q01 * e11;
  float u10 = q10 * e00 + q11 * e10, u11 = q10 * e01 + q11 * e11;
  float w00 = u00 * q00 + u01 * q01;
  float w01 = u00 * q10 + u01 * q11;
  float w10 = u10 * q00 + u11 * q01;
  float w11 = u10 * q10 + u11 * q11;
  float gauss = w00 * w11 - w01 * w10;
  if (lane == 0)
    atomicAdd(out, gauss * sva[0] * 0.15915494309189535f);  // * 1/(2*pi)
}

extern "C" void kernel_launch(void* const* d_in, const int* in_sizes, int n_in,
                              void* d_out, int out_size, void* d_ws, size_t ws_size,
                              hipStream_t stream) {
  const float* pts = (const float*)d_in[0];
  float* out = (float*)d_out;
  const int N = in_sizes[0] / 3;   // 4096
  knn_kernel<<<N, 256, 0, stream>>>(pts, out, N);
  frames_kernel<<<N / 4, 256, 0, stream>>>(pts, N);
  voro_curv_kernel<<<N, 256, 0, stream>>>(out, N);
}

// Round 15
// 168.517 us; speedup vs baseline: 1.1448x; 1.1448x over previous
//
#include <hip/hip_runtime.h>
#include <math.h>

#define NPTS 4096
#define KNB  50
#define WGRID 64

// ---------------- device scratch (written every launch before read) ----------------
__device__ int    g_idx[NPTS * KNB];
__device__ float  g_dt[NPTS * KNB * 2];
__device__ float  g_nrm[NPTS * 3];
__device__ float  g_t1[NPTS * 3];
__device__ float  g_t2[NPTS * 3];
__device__ float  g_bmin[NPTS * 2];
__device__ float  g_ml[NPTS];
__device__ float  g_va[NPTS];
__device__ float4 g_pq[NPTS];                 // packed (x, y, z, |p|^2)

// ---------------- LAPACK-faithful helpers (fp32, branch-structure identical) -------
__device__ __forceinline__ float slapy2f(float x, float y) {
  float ax = fabsf(x), ay = fabsf(y);
  float w = fmaxf(ax, ay), z = fminf(ax, ay);
  if (z == 0.0f) return w;
  float t = z / w;
  return w * sqrtf(1.0f + t * t);
}

// LAPACK >= 3.10 slartg (c >= 0 convention)
__device__ __forceinline__ void slartgf(float f, float g, float* cs, float* sn, float* r) {
  const float safmin = 1.1754944e-38f;
  const float safmax = 8.5070592e+37f;
  const float rtmin = 1.0842022e-19f;
  const float rtmax = 6.5219496e+18f;
  if (g == 0.0f) {
    *cs = 1.0f; *sn = 0.0f; *r = f;
  } else if (f == 0.0f) {
    *cs = 0.0f; *sn = copysignf(1.0f, g); *r = fabsf(g);
  } else {
    float f1 = fabsf(f), g1 = fabsf(g);
    if (f1 > rtmin && f1 < rtmax && g1 > rtmin && g1 < rtmax) {
      float d = sqrtf(f * f + g * g);
      float p = 1.0f / d;
      *cs = f1 * p;
      *sn = g * copysignf(p, f);
      *r = copysignf(d, f);
    } else {
      float u = fminf(safmax, fmaxf(safmin, fmaxf(f1, g1)));
      float fs = f / u, gs = g / u;
      float d = sqrtf(fs * fs + gs * gs);
      float p = 1.0f / d;
      *cs = fabsf(fs) * p;
      *sn = gs * copysignf(p, f);
      *r = copysignf(d, f) * u;
    }
  }
}

__device__ void slaev2f(float a, float b, float c, float* rt1, float* rt2,
                        float* cs1, float* sn1) {
  float sm = a + c;
  float df = a - c;
  float adf = fabsf(df);
  float tb = b + b;
  float ab = fabsf(tb);
  float acmx, acmn;
  if (fabsf(a) > fabsf(c)) { acmx = a; acmn = c; } else { acmx = c; acmn = a; }
  float rt;
  if (adf > ab)      { float t = ab / adf; rt = adf * sqrtf(1.0f + t * t); }
  else if (adf < ab) { float t = adf / ab; rt = ab * sqrtf(1.0f + t * t); }
  else               { rt = ab * sqrtf(2.0f); }
  int sgn1;
  if (sm < 0.0f) {
    *rt1 = 0.5f * (sm - rt); sgn1 = -1;
    *rt2 = (acmx / *rt1) * acmn - (b / *rt1) * b;
  } else if (sm > 0.0f) {
    *rt1 = 0.5f * (sm + rt); sgn1 = 1;
    *rt2 = (acmx / *rt1) * acmn - (b / *rt1) * b;
  } else {
    *rt1 = 0.5f * rt; *rt2 = -0.5f * rt; sgn1 = 1;
  }
  float cs; int sgn2;
  if (df >= 0.0f) { cs = df + rt; sgn2 = 1; }
  else            { cs = df - rt; sgn2 = -1; }
  float acs = fabsf(cs);
  if (acs > ab) {
    float ct = -tb / cs;
    *sn1 = 1.0f / sqrtf(1.0f + ct * ct);
    *cs1 = ct * (*sn1);
  } else {
    if (ab == 0.0f) { *cs1 = 1.0f; *sn1 = 0.0f; }
    else {
      float tn = -cs / tb;
      *cs1 = 1.0f / sqrtf(1.0f + tn * tn);
      *sn1 = tn * (*cs1);
    }
  }
  if (sgn1 == sgn2) { float tn = *cs1; *cs1 = -(*sn1); *sn1 = tn; }
}

// ssteqr, n=3, COMPZ='I'.
__device__ void ssteqr3(float* d, float* e, float Z[3][3]) {
  const float eps = 5.9604645e-08f;
  const float eps2 = 3.5527137e-15f;
  const float safmin = 1.1754944e-38f;
  const float ssfmax = 3.0744574e+18f;
  const float ssfmin = 3.0517578e-05f;
  const int n = 3, nmaxit = 90;
  int jtot = 0;
  for (int r = 0; r < 3; ++r)
    for (int c = 0; c < 3; ++c) Z[r][c] = (r == c) ? 1.0f : 0.0f;

  int l1 = 1;
  while (l1 <= n) {
    if (l1 > 1) e[l1 - 2] = 0.0f;
    int m = n;
    for (int mm = l1; mm <= n - 1; ++mm) {
      float tst = fabsf(e[mm - 1]);
      if (tst == 0.0f) { m = mm; break; }
      if (tst <= (sqrtf(fabsf(d[mm - 1])) * sqrtf(fabsf(d[mm]))) * eps) {
        e[mm - 1] = 0.0f; m = mm; break;
      }
    }
    int l = l1, lsv = l1, lend = m, lendsv = m;
    l1 = m + 1;
    if (lend == l) continue;

    float anorm = 0.0f;
    for (int ii = l; ii <= lend; ++ii) anorm = fmaxf(anorm, fabsf(d[ii - 1]));
    for (int ii = l; ii <= lend - 1; ++ii) anorm = fmaxf(anorm, fabsf(e[ii - 1]));
    if (anorm == 0.0f) continue;
    int iscale = 0;
    if (anorm > ssfmax) {
      iscale = 1; float mul = ssfmax / anorm;
      for (int ii = l; ii <= lend; ++ii) d[ii - 1] *= mul;
      for (int ii = l; ii <= lend - 1; ++ii) e[ii - 1] *= mul;
    } else if (anorm < ssfmin) {
      iscale = 2; float mul = ssfmin / anorm;
      for (int ii = l; ii <= lend; ++ii) d[ii - 1] *= mul;
      for (int ii = l; ii <= lend - 1; ++ii) e[ii - 1] *= mul;
    }
    if (fabsf(d[lend - 1]) < fabsf(d[l - 1])) { lend = lsv; l = lendsv; }

    if (lend > l) {
      for (;;) {
        int mm = lend;
        if (l != lend) {
          for (int t = l; t <= lend - 1; ++t) {
            float tst = e[t - 1] * e[t - 1];
            if (tst <= (eps2 * fabsf(d[t - 1])) * fabsf(d[t]) + safmin) { mm = t; break; }
          }
        }
        if (mm < lend) e[mm - 1] = 0.0f;
        float p = d[l - 1];
        if (mm == l) {
          d[l - 1] = p; ++l;
          if (l <= lend) continue; break;
        }
        if (mm == l + 1) {
          float rt1, rt2, c, s;
          slaev2f(d[l - 1], e[l - 1], d[l], &rt1, &rt2, &c, &s);
          for (int r = 0; r < 3; ++r) {
            float t = Z[r][l];
            Z[r][l]     = c * t - s * Z[r][l - 1];
            Z[r][l - 1] = s * t + c * Z[r][l - 1];
          }
          d[l - 1] = rt1; d[l] = rt2; e[l - 1] = 0.0f;
          l += 2;
          if (l <= lend) continue; break;
        }
        if (jtot == nmaxit) break;
        ++jtot;
        float g = (d[l] - p) / (2.0f * e[l - 1]);
        float r = slapy2f(g, 1.0f);
        g = d[mm - 1] - p + e[l - 1] / (g + copysignf(r, g));
        float s = 1.0f, c = 1.0f;
        p = 0.0f;
        float cw[2], sw[2];
        for (int i = mm - 1; i >= l; --i) {
          float f = s * e[i - 1];
          float b = c * e[i - 1];
          slartgf(g, f, &c, &s, &r);
          if (i != mm - 1) e[i] = r;
          g = d[i] - p;
          r = (d[i - 1] - g) * s + 2.0f * c * b;
          p = s * r;
          d[i] = g + p;
          g = c * r - b;
          cw[i - l] = c; sw[i - l] = -s;
        }
        for (int j = mm - 1; j >= l; --j) {
          float cc = cw[j - l], ss = sw[j - l];
          for (int r2 = 0; r2 < 3; ++r2) {
            float t = Z[r2][j];
            Z[r2][j]     = cc * t - ss * Z[r2][j - 1];
            Z[r2][j - 1] = ss * t + cc * Z[r2][j - 1];
          }
        }
        d[l - 1] -= p;
        e[l - 1] = g;
      }
    } else {
      for (;;) {
        int mm = lend;
        if (l != lend) {
          for (int t = l; t >= lend + 1; --t) {
            float tst = e[t - 2] * e[t - 2];
            if (tst <= (eps2 * fabsf(d[t - 1])) * fabsf(d[t - 2]) + safmin) { mm = t; break; }
          }
        }
        if (mm > lend) e[mm - 2] = 0.0f;
        float p = d[l - 1];
        if (mm == l) {
          d[l - 1] = p; --l;
          if (l >= lend) continue; break;
        }
        if (mm == l - 1) {
          float rt1, rt2, c, s;
          slaev2f(d[l - 2], e[l - 2], d[l - 1], &rt1, &rt2, &c, &s);
          for (int r2 = 0; r2 < 3; ++r2) {
            float t = Z[r2][l - 1];
            Z[r2][l - 1] = c * t - s * Z[r2][l - 2];
            Z[r2][l - 2] = s * t + c * Z[r2][l - 2];
          }
          d[l - 2] = rt1; d[l - 1] = rt2; e[l - 2] = 0.0f;
          l -= 2;
          if (l >= lend) continue; break;
        }
        if (jtot == nmaxit) break;
        ++jtot;
        float g = (d[l - 2] - p) / (2.0f * e[l - 2]);
        float r = slapy2f(g, 1.0f);
        g = d[mm - 1] - p + e[l - 2] / (g + copysignf(r, g));
        float s = 1.0f, c = 1.0f;
        p = 0.0f;
        float cw[2], sw[2];
        for (int i = mm; i <= l - 1; ++i) {
          float f = s * e[i - 1];
          float b = c * e[i - 1];
          slartgf(g, f, &c, &s, &r);
          if (i != mm) e[i - 2] = r;
          g = d[i - 1] - p;
          r = (d[i] - g) * s + 2.0f * c * b;
          p = s * r;
          d[i - 1] = g + p;
          g = c * r - b;
          cw[i - mm] = c; sw[i - mm] = s;
        }
        for (int j = mm; j <= l - 1; ++j) {
          float cc = cw[j - mm], ss = sw[j - mm];
          for (int r2 = 0; r2 < 3; ++r2) {
            float t = Z[r2][j];
            Z[r2][j]     = cc * t - ss * Z[r2][j - 1];
            Z[r2][j - 1] = ss * t + cc * Z[r2][j - 1];
          }
        }
        d[l - 1] -= p;
        e[l - 2] = g;
      }
    }
    if (iscale == 1) {
      float mul = anorm / ssfmax;
      for (int ii = lsv; ii <= lendsv; ++ii) d[ii - 1] *= mul;
      for (int ii = lsv; ii <= lendsv - 1; ++ii) e[ii - 1] *= mul;
    } else if (iscale == 2) {
      float mul = anorm / ssfmin;
      for (int ii = lsv; ii <= lendsv; ++ii) d[ii - 1] *= mul;
      for (int ii = lsv; ii <= lendsv - 1; ++ii) e[ii - 1] *= mul;
    }
    if (jtot >= nmaxit) break;
  }
  for (int ii = 2; ii <= n; ++ii) {
    int i0 = ii - 1, k0 = i0;
    float p = d[i0 - 1];
    for (int j = ii; j <= n; ++j)
      if (d[j - 1] < p) { k0 = j; p = d[j - 1]; }
    if (k0 != i0) {
      d[k0 - 1] = d[i0 - 1]; d[i0 - 1] = p;
      for (int r2 = 0; r2 < 3; ++r2) {
        float t = Z[r2][i0 - 1]; Z[r2][i0 - 1] = Z[r2][k0 - 1]; Z[r2][k0 - 1] = t;
      }
    }
  }
}

__device__ void ssytrd3(float a11, float a21, float a31, float a22, float a32, float a33,
                        float d[3], float e[2], float* tau, float* u) {
  float xnorm = fabsf(a31);
  if (xnorm == 0.0f) {
    *tau = 0.0f; *u = 0.0f;
    d[0] = a11; d[1] = a22; d[2] = a33; e[0] = a21; e[1] = a32;
    return;
  }
  float beta = -copysignf(slapy2f(a21, xnorm), a21);
  float taui = (beta - a21) / beta;
  float uu = a31 * (1.0f / (a21 - beta));
  float w1 = taui * a22 + taui * (a32 * uu);
  float w2 = taui * a32 + (taui * uu) * a33;
  float alpha = -0.5f * taui * (w1 + w2 * uu);
  w1 += alpha; w2 += alpha * uu;
  float na22 = a22 - 2.0f * w1;
  float na32 = a32 - (uu * w1 + w2);
  float na33 = a33 - 2.0f * (uu * w2);
  d[0] = a11; d[1] = na22; d[2] = na33;
  e[0] = beta; e[1] = na32;
  *tau = taui; *u = uu;
}

// ---------------- K0: pack points as (x,y,z,|p|^2) — d2 expression matches knn -----
__global__ __launch_bounds__(256) void prep_kernel(const float* __restrict__ pts,
                                                   float* __restrict__ out, int N) {
  int j = blockIdx.x * 256 + threadIdx.x;
  if (j == 0) out[0] = 0.0f;                    // curv accumulates atomically later
  if (j < N) {
    float xj = pts[3 * j], yj = pts[3 * j + 1], zj = pts[3 * j + 2];
    float d2j = xj * xj + yj * yj + zj * zj;    // identical expression to R1..R14
    g_pq[j] = make_float4(xj, yj, zj, d2j);
  }
}

// ---------------- K1: kNN via 2x8-bit radix-select, float4 loads -------------------
// R12's exact selection logic; sweep-1/3 read the packed float4 (one dwordx4 per
// point, d2 preloaded) — dist bits unchanged since d2j is the same expression.
__global__ __launch_bounds__(256) void knn_kernel(const float* __restrict__ pts, int N) {
  __shared__ unsigned skey[NPTS];      // 16 KB
  __shared__ unsigned hist[256];
  __shared__ unsigned sred[4];
  __shared__ unsigned sbin[2];
  __shared__ int   eqi[64];
  __shared__ float eqd[64];
  __shared__ unsigned eqn[1];
  const int i = blockIdx.x;
  const int tid = threadIdx.x;
  const int lane = tid & 63, wid = tid >> 6;
  const float xi = pts[3 * i], yi = pts[3 * i + 1], zi = pts[3 * i + 2];
  const float d2i = xi * xi + yi * yi + zi * zi;
  hist[tid] = 0;
  if (tid == 0) eqn[0] = 0;
  __syncthreads();
  for (int j = tid; j < N; j += 256) {
    float4 p = g_pq[j];
    float dot = fmaf(zi, p.z, fmaf(yi, p.y, xi * p.x));
    float dist = (d2i - 2.0f * dot) + p.w;        // identical bits to R1..R14
    float dc = fminf(fmaxf(dist, 0.0f), 31.0f);
    unsigned u = (unsigned)(dc * 134217728.0f);   // *2^27 exact, trunc: monotone
    skey[j] = u;
    atomicAdd(&hist[u >> 24], 1u);                // fused pass-0 histogram
  }
  __syncthreads();
  unsigned prefix = 0, rank = 49;
  for (int pass = 0; pass < 2; ++pass) {
    const int shift = 24 - 8 * pass;
    if (pass) {
      for (int j = tid; j < N; j += 256) {
        unsigned u = skey[j];
        if ((u >> 24) == (prefix >> 24))
          atomicAdd(&hist[(u >> 16) & 255u], 1u);
      }
      __syncthreads();
    }
    unsigned h = hist[tid];
    unsigned c = h;
    #pragma unroll
    for (int off = 1; off < 64; off <<= 1) {
      unsigned o = __shfl_up(c, off);
      if (lane >= off) c += o;
    }
    if (lane == 63) sred[wid] = c;
    __syncthreads();
    unsigned wbase = 0;
    for (int w2 = 0; w2 < wid; ++w2) wbase += sred[w2];
    c += wbase;
    unsigned excl = c - h;
    if (rank >= excl && rank < c) { sbin[0] = (unsigned)tid; sbin[1] = rank - excl; }
    __syncthreads();
    prefix |= sbin[0] << shift;
    rank = sbin[1];
    __syncthreads();
    if (pass == 0) { hist[tid] = 0; __syncthreads(); }
  }
  const unsigned T = prefix;                      // low 16 bits zero
  int cnt = 0;
  for (int j = tid; j < N; j += 256) {
    unsigned u = skey[j];
    if (u < T && j != i) {
      ++cnt;
    } else if ((u & 0xFFFF0000u) == T) {
      float4 p = g_pq[j];
      float dot = fmaf(zi, p.z, fmaf(yi, p.y, xi * p.x));
      float dist = (d2i - 2.0f * dot) + p.w;
      unsigned e = atomicAdd(&eqn[0], 1u);
      if (e < 64u) { eqi[e] = j; eqd[e] = dist; }
    }
  }
  __syncthreads();
  unsigned cc = (unsigned)cnt;
  #pragma unroll
  for (int off = 1; off < 64; off <<= 1) {
    unsigned o = __shfl_up(cc, off);
    if (lane >= off) cc += o;
  }
  if (lane == 63) sred[wid] = cc;
  __syncthreads();
  unsigned wbase = 0;
  for (int w2 = 0; w2 < wid; ++w2) wbase += sred[w2];
  int base = 1 + (int)(wbase + cc - (unsigned)cnt);  // deterministic compaction slot
  for (int j = tid; j < N; j += 256) {
    unsigned u = skey[j];
    if (u < T && j != i) g_idx[i * KNB + (base++)] = j;
  }
  if (tid == 0) {
    g_idx[i * KNB] = i;                            // self = global min distance
    int slot = 1 + (int)(sred[0] + sred[1] + sred[2] + sred[3]);
    int need = KNB - slot;                         // >= 1
    int ne = (int)eqn[0]; if (ne > 64) ne = 64;
    for (int e2 = 0; e2 < need; ++e2) {            // exact (dist, index) ascending
      int bq = 0, bidx = 0x7FFFFFFF; float bd = 3.4e38f;
      for (int q = 0; q < ne; ++q) {
        if (eqi[q] < 0) continue;
        float dq = eqd[q];
        if (dq < bd || (dq == bd && eqi[q] < bidx)) { bd = dq; bidx = eqi[q]; bq = q; }
      }
      g_idx[i * KNB + slot + e2] = bidx;
      eqi[bq] = -1;
    }
  }
}

// ---------------- K2: frames, wave-per-point (exact R2 accumulation order) ---------
__global__ __launch_bounds__(256) void frames_kernel(const float* __restrict__ pts, int N) {
  __shared__ float sx[4][52], sy[4][52], sz[4][52];
  const int tid = threadIdx.x, lane = tid & 63, w = tid >> 6;
  const int i = blockIdx.x * 4 + w;
  const int base = i * KNB;
  if (lane < KNB) {
    int j = g_idx[base + lane];
    sx[w][lane] = pts[3 * j];
    sy[w][lane] = pts[3 * j + 1];
    sz[w][lane] = pts[3 * j + 2];
  }
  __syncthreads();
  float mx = 0.0f, my = 0.0f, mz = 0.0f;
  for (int kk = 0; kk < KNB; ++kk) { mx += sx[w][kk]; my += sy[w][kk]; mz += sz[w][kk]; }
  mx /= 50.0f; my /= 50.0f; mz /= 50.0f;
  float c00 = 0, c01 = 0, c02 = 0, c11 = 0, c12 = 0, c22 = 0;
  for (int kk = 0; kk < KNB; ++kk) {
    float cx = sx[w][kk] - mx, cy = sy[w][kk] - my, cz = sz[w][kk] - mz;
    c00 = fmaf(cx, cx, c00); c01 = fmaf(cx, cy, c01); c02 = fmaf(cx, cz, c02);
    c11 = fmaf(cy, cy, c11); c12 = fmaf(cy, cz, c12); c22 = fmaf(cz, cz, c22);
  }
  c00 *= 0.5f; c01 *= 0.5f; c02 *= 0.5f; c11 *= 0.5f; c12 *= 0.5f; c22 *= 0.5f;

  float d[3], e[2], tau, u;
  ssytrd3(c00, c01, c02, c11, c12, c22, d, e, &tau, &u);
  float Z[3][3];
  ssteqr3(d, e, Z);
  if (tau != 0.0f) {
    for (int c = 0; c < 3; ++c) {
      float sum = Z[1][c] + u * Z[2][c];
      Z[1][c] -= tau * sum;
      Z[2][c] -= tau * u * sum;
    }
  }
  float n0 = Z[0][0], n1 = Z[1][0], n2 = Z[2][0];
  float a0 = Z[0][1], a1 = Z[1][1], a2 = Z[2][1];
  float b0 = Z[0][2], b1 = Z[1][2], b2 = Z[2][2];
  float cxp = a1 * b2 - a2 * b1, cyp = a2 * b0 - a0 * b2, czp = a0 * b1 - a1 * b0;
  float det = n0 * cxp + n1 * cyp + n2 * czp;
  a0 *= det; a1 *= det; a2 *= det;

  const float xi = pts[3 * i], yi = pts[3 * i + 1], zi = pts[3 * i + 2];
  float dt0 = 0.0f, dt1 = 0.0f;
  float mn0 = 3.0e38f, mx0 = -3.0e38f, mn1 = 3.0e38f, mx1 = -3.0e38f;
  if (lane < KNB) {
    float dx = sx[w][lane] - xi, dy = sy[w][lane] - yi, dz = sz[w][lane] - zi;
    dt0 = dx * a0 + dy * a1 + dz * a2;
    dt1 = dx * b0 + dy * b1 + dz * b2;
    g_dt[2 * (base + lane)] = dt0;
    g_dt[2 * (base + lane) + 1] = dt1;
    mn0 = dt0; mx0 = dt0; mn1 = dt1; mx1 = dt1;
  }
  #pragma unroll
  for (int off = 32; off > 0; off >>= 1) {
    mn0 = fminf(mn0, __shfl_down(mn0, off));
    mx0 = fmaxf(mx0, __shfl_down(mx0, off));
    mn1 = fminf(mn1, __shfl_down(mn1, off));
    mx1 = fmaxf(mx1, __shfl_down(mx1, off));
  }
  if (lane == 0) {
    g_nrm[3 * i] = n0; g_nrm[3 * i + 1] = n1; g_nrm[3 * i + 2] = n2;
    g_t1[3 * i] = a0;  g_t1[3 * i + 1] = a1;  g_t1[3 * i + 2] = a2;
    g_t2[3 * i] = b0;  g_t2[3 * i + 1] = b1;  g_t2[3 * i + 2] = b2;
    float bmin0 = mn0 * 1.1f, bmax0 = mx0 * 1.1f;
    float bmin1 = mn1 * 1.1f, bmax1 = mx1 * 1.1f;
    float ml = fmaxf(bmax0 - bmin0, bmax1 - bmin1);
    g_bmin[2 * i] = bmin0; g_bmin[2 * i + 1] = bmin1;
    g_ml[i] = ml;
  }
}

// ---------------- K3: Voronoi — exact linear block pruning (R12 exact code) --------
__global__ __launch_bounds__(256, 8) void voronoi_kernel(int N) {
  __shared__ float2 sc[KNB];
  __shared__ int alist[64];
  __shared__ int acnt[1];
  __shared__ int swc[4];
  const int i = blockIdx.x;
  const int tid = threadIdx.x;
  const int lane = tid & 63, wid = tid >> 6;   // 4 waves
  const float ml = g_ml[i];
  const float b0 = g_bmin[2 * i], b1 = g_bmin[2 * i + 1];
  if (tid < KNB) {
    float dt0 = g_dt[2 * (i * KNB + tid)];
    float dt1 = g_dt[2 * (i * KNB + tid) + 1];
    sc[tid] = make_float2((dt0 - b0) / ml * 2.0f - 1.0f,
                          (dt1 - b1) / ml * 2.0f - 1.0f);
  }
  if (tid == 0) acnt[0] = 0;
  __syncthreads();
  const float step = 2.0f / 63.0f;
  if (tid < 64) {
    const int bx = tid & 7, by = tid >> 3;
    const float gx0 = fmaf((float)(bx * 8), step, -1.0f);
    const float gx1 = fmaf((float)(bx * 8 + 7), step, -1.0f);
    const float gy0 = fmaf((float)(by * 8), step, -1.0f);
    const float gy1 = fmaf((float)(by * 8 + 7), step, -1.0f);
    const float s0x = sc[0].x, s0y = sc[0].y;
    const float n0s = s0x * s0x + s0y * s0y;
    bool dead = false;
    #pragma clang loop unroll(disable)
    for (int j = 1; j < KNB && !dead; ++j) {
      float sx = sc[j].x, sy = sc[j].y;
      float ax2 = 2.0f * (sx - s0x), ay2 = 2.0f * (sy - s0y);
      float cst = n0s - (sx * sx + sy * sy);
      float Lmin = fminf(ax2 * gx0, ax2 * gx1) + fminf(ay2 * gy0, ay2 * gy1) + cst;
      dead = Lmin > 1e-4f;
    }
    if (!dead) { int p = atomicAdd(&acnt[0], 1); alist[p] = tid; }
  }
  __syncthreads();
  const int na = acnt[0];
  const float c0x = sc[0].x, c0y = sc[0].y;
  int cnt = 0;
  #pragma clang loop unroll(disable)
  for (int k = wid; k < na; k += 4) {
    int b = alist[k];
    int ix = (b & 7) * 8 + (lane & 7);
    int iy = (b >> 3) * 8 + (lane >> 3);
    float gx = fmaf((float)ix, step, -1.0f);
    float gy = fmaf((float)iy, step, -1.0f);
    float ex = gx - c0x, ey = gy - c0y;
    float d0 = ex * ex + ey * ey;
    float m = 3.0e38f;
    #pragma clang loop unroll(disable)
    for (int j = 1; j < KNB; ++j) {
      float dx = gx - sc[j].x, dy = gy - sc[j].y;
      float dd = fmaf(dx, dx, dy * dy);
      m = fminf(m, dd);
    }
    cnt += (d0 <= m) ? 1 : 0;
  }
  #pragma unroll
  for (int off = 32; off > 0; off >>= 1) cnt += __shfl_down(cnt, off);
  if (lane == 0) swc[wid] = cnt;
  __syncthreads();
  if (tid == 0) {
    int tot = swc[0] + swc[1] + swc[2] + swc[3];
    g_va[i] = (float)tot * (ml * ml) / 3969.0f;
  }
}

// ---------------- K4: Weingarten fit + atomic global sum (R12 exact code) ----------
__global__ __launch_bounds__(256) void curv_kernel(float* __restrict__ out, int N) {
  __shared__ float s0[4][52], s1[4][52], tx[4][52], ty[4][52], tz[4][52];
  __shared__ float bsum[4];
  const int tid = threadIdx.x, lane = tid & 63, w = tid >> 6;
  const int i = blockIdx.x * 4 + w;
  const int base = i * KNB;
  if (lane < KNB) {
    int j = g_idx[base + lane];
    s0[w][lane] = g_dt[2 * (base + lane)];
    s1[w][lane] = g_dt[2 * (base + lane) + 1];
    tx[w][lane] = g_nrm[3 * j];
    ty[w][lane] = g_nrm[3 * j + 1];
    tz[w][lane] = g_nrm[3 * j + 2];
  }
  __syncthreads();
  float nx = g_nrm[3 * i], ny = g_nrm[3 * i + 1], nz = g_nrm[3 * i + 2];
  float ax = g_t1[3 * i], ay = g_t1[3 * i + 1], az = g_t1[3 * i + 2];
  float bx = g_t2[3 * i], by = g_t2[3 * i + 1], bz = g_t2[3 * i + 2];
  float xx = 0, xy = 0, yy = 0;
  float y00 = 0, y01 = 0, y10 = 0, y11 = 0;
  for (int kk = 0; kk < KNB; ++kk) {
    float dt0 = s0[w][kk], dt1 = s1[w][kk];
    float lx = tx[w][kk] - nx, ly = ty[w][kk] - ny, lz = tz[w][kk] - nz;
    float dn0 = lx * ax + ly * ay + lz * az;
    float dn1 = lx * bx + ly * by + lz * bz;
    xx = fmaf(dt0, dt0, xx); xy = fmaf(dt0, dt1, xy); yy = fmaf(dt1, dt1, yy);
    y00 = fmaf(dn0, dt0, y00); y01 = fmaf(dn0, dt1, y01);
    y10 = fmaf(dn1, dt0, y10); y11 = fmaf(dn1, dt1, y11);
  }
  float s00 = y00 + y00, s01 = y01 + y10, s11 = y11 + y11;
  float rt1, rt2, cs1, sn1;
  slaev2f(xx, xy, yy, &rt1, &rt2, &cs1, &sn1);
  float a, bb, q00, q10, q01, q11;
  if (rt1 <= rt2) { a = rt1; bb = rt2; q00 = cs1; q10 = sn1; q01 = -sn1; q11 = cs1; }
  else            { a = rt2; bb = rt1; q00 = -sn1; q10 = cs1; q01 = cs1; q11 = sn1; }
  float t00 = s00 * q00 + s01 * q10, t01 = s00 * q01 + s01 * q11;
  float t10 = s01 * q00 + s11 * q10, t11 = s01 * q01 + s11 * q11;
  float m00 = q00 * t00 + q10 * t10;
  float m01 = q00 * t01 + q10 * t11;
  float m10 = q01 * t00 + q11 * t10;
  float m11 = q01 * t01 + q11 * t11;
  float e00 = m00 / (2.0f * a + 1e-8f);
  float e01 = m01 / ((a + bb) + 1e-8f);
  float e10 = m10 / ((a + bb) + 1e-8f);
  float e11 = m11 / (2.0f * bb + 1e-8f);
  float u00 = q00 * e00 + q01 * e10, u01 = q00 * e01 + q01 * e11;
  float u10 = q10 * e00 + q11 * e10, u11 = q10 * e01 + q11 * e11;
  float w00 = u00 * q00 + u01 * q01;
  float w01 = u00 * q10 + u01 * q11;
  float w10 = u10 * q00 + u11 * q01;
  float w11 = u10 * q10 + u11 * q11;
  float gauss = w00 * w11 - w01 * w10;
  if (lane == 0) bsum[w] = gauss * g_va[i] * 0.15915494309189535f;  // /(2*pi)
  __syncthreads();
  if (tid == 0)
    atomicAdd(out, bsum[0] + bsum[1] + bsum[2] + bsum[3]);  // one atomic per block
}

extern "C" void kernel_launch(void* const* d_in, const int* in_sizes, int n_in,
                              void* d_out, int out_size, void* d_ws, size_t ws_size,
                              hipStream_t stream) {
  const float* pts = (const float*)d_in[0];
  float* out = (float*)d_out;
  const int N = in_sizes[0] / 3;   // 4096
  prep_kernel<<<(N + 255) / 256, 256, 0, stream>>>(pts, out, N);
  knn_kernel<<<N, 256, 0, stream>>>(pts, N);
  frames_kernel<<<N / 4, 256, 0, stream>>>(pts, N);
  voronoi_kernel<<<N, 256, 0, stream>>>(N);
  curv_kernel<<<N / 4, 256, 0, stream>>>(out, N);
}

// Round 16
// 166.909 us; speedup vs baseline: 1.1559x; 1.0096x over previous
//
#include <hip/hip_runtime.h>
#include <math.h>

#define NPTS 4096
#define KNB  50
#define WGRID 64

// ---------------- device scratch (written every launch before read) ----------------
__device__ int   g_idx[NPTS * KNB];
__device__ float g_dt[NPTS * KNB * 2];
__device__ float g_nrm[NPTS * 3];
__device__ float g_t1[NPTS * 3];
__device__ float g_t2[NPTS * 3];
__device__ float g_bmin[NPTS * 2];
__device__ float g_ml[NPTS];
__device__ float g_va[NPTS];

// ---------------- LAPACK-faithful helpers (fp32, branch-structure identical) -------
__device__ __forceinline__ float slapy2f(float x, float y) {
  float ax = fabsf(x), ay = fabsf(y);
  float w = fmaxf(ax, ay), z = fminf(ax, ay);
  if (z == 0.0f) return w;
  float t = z / w;
  return w * sqrtf(1.0f + t * t);
}

// LAPACK >= 3.10 slartg (c >= 0 convention)
__device__ __forceinline__ void slartgf(float f, float g, float* cs, float* sn, float* r) {
  const float safmin = 1.1754944e-38f;
  const float safmax = 8.5070592e+37f;
  const float rtmin = 1.0842022e-19f;
  const float rtmax = 6.5219496e+18f;
  if (g == 0.0f) {
    *cs = 1.0f; *sn = 0.0f; *r = f;
  } else if (f == 0.0f) {
    *cs = 0.0f; *sn = copysignf(1.0f, g); *r = fabsf(g);
  } else {
    float f1 = fabsf(f), g1 = fabsf(g);
    if (f1 > rtmin && f1 < rtmax && g1 > rtmin && g1 < rtmax) {
      float d = sqrtf(f * f + g * g);
      float p = 1.0f / d;
      *cs = f1 * p;
      *sn = g * copysignf(p, f);
      *r = copysignf(d, f);
    } else {
      float u = fminf(safmax, fmaxf(safmin, fmaxf(f1, g1)));
      float fs = f / u, gs = g / u;
      float d = sqrtf(fs * fs + gs * gs);
      float p = 1.0f / d;
      *cs = fabsf(fs) * p;
      *sn = gs * copysignf(p, f);
      *r = copysignf(d, f) * u;
    }
  }
}

__device__ void slaev2f(float a, float b, float c, float* rt1, float* rt2,
                        float* cs1, float* sn1) {
  float sm = a + c;
  float df = a - c;
  float adf = fabsf(df);
  float tb = b + b;
  float ab = fabsf(tb);
  float acmx, acmn;
  if (fabsf(a) > fabsf(c)) { acmx = a; acmn = c; } else { acmx = c; acmn = a; }
  float rt;
  if (adf > ab)      { float t = ab / adf; rt = adf * sqrtf(1.0f + t * t); }
  else if (adf < ab) { float t = adf / ab; rt = ab * sqrtf(1.0f + t * t); }
  else               { rt = ab * sqrtf(2.0f); }
  int sgn1;
  if (sm < 0.0f) {
    *rt1 = 0.5f * (sm - rt); sgn1 = -1;
    *rt2 = (acmx / *rt1) * acmn - (b / *rt1) * b;
  } else if (sm > 0.0f) {
    *rt1 = 0.5f * (sm + rt); sgn1 = 1;
    *rt2 = (acmx / *rt1) * acmn - (b / *rt1) * b;
  } else {
    *rt1 = 0.5f * rt; *rt2 = -0.5f * rt; sgn1 = 1;
  }
  float cs; int sgn2;
  if (df >= 0.0f) { cs = df + rt; sgn2 = 1; }
  else            { cs = df - rt; sgn2 = -1; }
  float acs = fabsf(cs);
  if (acs > ab) {
    float ct = -tb / cs;
    *sn1 = 1.0f / sqrtf(1.0f + ct * ct);
    *cs1 = ct * (*sn1);
  } else {
    if (ab == 0.0f) { *cs1 = 1.0f; *sn1 = 0.0f; }
    else {
      float tn = -cs / tb;
      *cs1 = 1.0f / sqrtf(1.0f + tn * tn);
      *sn1 = tn * (*cs1);
    }
  }
  if (sgn1 == sgn2) { float tn = *cs1; *cs1 = -(*sn1); *sn1 = tn; }
}

// ssteqr, n=3, COMPZ='I'.
__device__ void ssteqr3(float* d, float* e, float Z[3][3]) {
  const float eps = 5.9604645e-08f;
  const float eps2 = 3.5527137e-15f;
  const float safmin = 1.1754944e-38f;
  const float ssfmax = 3.0744574e+18f;
  const float ssfmin = 3.0517578e-05f;
  const int n = 3, nmaxit = 90;
  int jtot = 0;
  for (int r = 0; r < 3; ++r)
    for (int c = 0; c < 3; ++c) Z[r][c] = (r == c) ? 1.0f : 0.0f;

  int l1 = 1;
  while (l1 <= n) {
    if (l1 > 1) e[l1 - 2] = 0.0f;
    int m = n;
    for (int mm = l1; mm <= n - 1; ++mm) {
      float tst = fabsf(e[mm - 1]);
      if (tst == 0.0f) { m = mm; break; }
      if (tst <= (sqrtf(fabsf(d[mm - 1])) * sqrtf(fabsf(d[mm]))) * eps) {
        e[mm - 1] = 0.0f; m = mm; break;
      }
    }
    int l = l1, lsv = l1, lend = m, lendsv = m;
    l1 = m + 1;
    if (lend == l) continue;

    float anorm = 0.0f;
    for (int ii = l; ii <= lend; ++ii) anorm = fmaxf(anorm, fabsf(d[ii - 1]));
    for (int ii = l; ii <= lend - 1; ++ii) anorm = fmaxf(anorm, fabsf(e[ii - 1]));
    if (anorm == 0.0f) continue;
    int iscale = 0;
    if (anorm > ssfmax) {
      iscale = 1; float mul = ssfmax / anorm;
      for (int ii = l; ii <= lend; ++ii) d[ii - 1] *= mul;
      for (int ii = l; ii <= lend - 1; ++ii) e[ii - 1] *= mul;
    } else if (anorm < ssfmin) {
      iscale = 2; float mul = ssfmin / anorm;
      for (int ii = l; ii <= lend; ++ii) d[ii - 1] *= mul;
      for (int ii = l; ii <= lend - 1; ++ii) e[ii - 1] *= mul;
    }
    if (fabsf(d[lend - 1]) < fabsf(d[l - 1])) { lend = lsv; l = lendsv; }

    if (lend > l) {
      for (;;) {
        int mm = lend;
        if (l != lend) {
          for (int t = l; t <= lend - 1; ++t) {
            float tst = e[t - 1] * e[t - 1];
            if (tst <= (eps2 * fabsf(d[t - 1])) * fabsf(d[t]) + safmin) { mm = t; break; }
          }
        }
        if (mm < lend) e[mm - 1] = 0.0f;
        float p = d[l - 1];
        if (mm == l) {
          d[l - 1] = p; ++l;
          if (l <= lend) continue; break;
        }
        if (mm == l + 1) {
          float rt1, rt2, c, s;
          slaev2f(d[l - 1], e[l - 1], d[l], &rt1, &rt2, &c, &s);
          for (int r = 0; r < 3; ++r) {
            float t = Z[r][l];
            Z[r][l]     = c * t - s * Z[r][l - 1];
            Z[r][l - 1] = s * t + c * Z[r][l - 1];
          }
          d[l - 1] = rt1; d[l] = rt2; e[l - 1] = 0.0f;
          l += 2;
          if (l <= lend) continue; break;
        }
        if (jtot == nmaxit) break;
        ++jtot;
        float g = (d[l] - p) / (2.0f * e[l - 1]);
        float r = slapy2f(g, 1.0f);
        g = d[mm - 1] - p + e[l - 1] / (g + copysignf(r, g));
        float s = 1.0f, c = 1.0f;
        p = 0.0f;
        float cw[2], sw[2];
        for (int i = mm - 1; i >= l; --i) {
          float f = s * e[i - 1];
          float b = c * e[i - 1];
          slartgf(g, f, &c, &s, &r);
          if (i != mm - 1) e[i] = r;
          g = d[i] - p;
          r = (d[i - 1] - g) * s + 2.0f * c * b;
          p = s * r;
          d[i] = g + p;
          g = c * r - b;
          cw[i - l] = c; sw[i - l] = -s;
        }
        for (int j = mm - 1; j >= l; --j) {
          float cc = cw[j - l], ss = sw[j - l];
          for (int r2 = 0; r2 < 3; ++r2) {
            float t = Z[r2][j];
            Z[r2][j]     = cc * t - ss * Z[r2][j - 1];
            Z[r2][j - 1] = ss * t + cc * Z[r2][j - 1];
          }
        }
        d[l - 1] -= p;
        e[l - 1] = g;
      }
    } else {
      for (;;) {
        int mm = lend;
        if (l != lend) {
          for (int t = l; t >= lend + 1; --t) {
            float tst = e[t - 2] * e[t - 2];
            if (tst <= (eps2 * fabsf(d[t - 1])) * fabsf(d[t - 2]) + safmin) { mm = t; break; }
          }
        }
        if (mm > lend) e[mm - 2] = 0.0f;
        float p = d[l - 1];
        if (mm == l) {
          d[l - 1] = p; --l;
          if (l >= lend) continue; break;
        }
        if (mm == l - 1) {
          float rt1, rt2, c, s;
          slaev2f(d[l - 2], e[l - 2], d[l - 1], &rt1, &rt2, &c, &s);
          for (int r2 = 0; r2 < 3; ++r2) {
            float t = Z[r2][l - 1];
            Z[r2][l - 1] = c * t - s * Z[r2][l - 2];
            Z[r2][l - 2] = s * t + c * Z[r2][l - 2];
          }
          d[l - 2] = rt1; d[l - 1] = rt2; e[l - 2] = 0.0f;
          l -= 2;
          if (l >= lend) continue; break;
        }
        if (jtot == nmaxit) break;
        ++jtot;
        float g = (d[l - 2] - p) / (2.0f * e[l - 2]);
        float r = slapy2f(g, 1.0f);
        g = d[mm - 1] - p + e[l - 2] / (g + copysignf(r, g));
        float s = 1.0f, c = 1.0f;
        p = 0.0f;
        float cw[2], sw[2];
        for (int i = mm; i <= l - 1; ++i) {
          float f = s * e[i - 1];
          float b = c * e[i - 1];
          slartgf(g, f, &c, &s, &r);
          if (i != mm) e[i - 2] = r;
          g = d[i - 1] - p;
          r = (d[i] - g) * s + 2.0f * c * b;
          p = s * r;
          d[i - 1] = g + p;
          g = c * r - b;
          cw[i - mm] = c; sw[i - mm] = s;
        }
        for (int j = mm; j <= l - 1; ++j) {
          float cc = cw[j - mm], ss = sw[j - mm];
          for (int r2 = 0; r2 < 3; ++r2) {
            float t = Z[r2][j];
            Z[r2][j]     = cc * t - ss * Z[r2][j - 1];
            Z[r2][j - 1] = ss * t + cc * Z[r2][j - 1];
          }
        }
        d[l - 1] -= p;
        e[l - 2] = g;
      }
    }
    if (iscale == 1) {
      float mul = anorm / ssfmax;
      for (int ii = lsv; ii <= lendsv; ++ii) d[ii - 1] *= mul;
      for (int ii = lsv; ii <= lendsv - 1; ++ii) e[ii - 1] *= mul;
    } else if (iscale == 2) {
      float mul = anorm / ssfmin;
      for (int ii = lsv; ii <= lendsv; ++ii) d[ii - 1] *= mul;
      for (int ii = lsv; ii <= lendsv - 1; ++ii) e[ii - 1] *= mul;
    }
    if (jtot >= nmaxit) break;
  }
  for (int ii = 2; ii <= n; ++ii) {
    int i0 = ii - 1, k0 = i0;
    float p = d[i0 - 1];
    for (int j = ii; j <= n; ++j)
      if (d[j - 1] < p) { k0 = j; p = d[j - 1]; }
    if (k0 != i0) {
      d[k0 - 1] = d[i0 - 1]; d[i0 - 1] = p;
      for (int r2 = 0; r2 < 3; ++r2) {
        float t = Z[r2][i0 - 1]; Z[r2][i0 - 1] = Z[r2][k0 - 1]; Z[r2][k0 - 1] = t;
      }
    }
  }
}

__device__ void ssytrd3(float a11, float a21, float a31, float a22, float a32, float a33,
                        float d[3], float e[2], float* tau, float* u) {
  float xnorm = fabsf(a31);
  if (xnorm == 0.0f) {
    *tau = 0.0f; *u = 0.0f;
    d[0] = a11; d[1] = a22; d[2] = a33; e[0] = a21; e[1] = a32;
    return;
  }
  float beta = -copysignf(slapy2f(a21, xnorm), a21);
  float taui = (beta - a21) / beta;
  float uu = a31 * (1.0f / (a21 - beta));
  float w1 = taui * a22 + taui * (a32 * uu);
  float w2 = taui * a32 + (taui * uu) * a33;
  float alpha = -0.5f * taui * (w1 + w2 * uu);
  w1 += alpha; w2 += alpha * uu;
  float na22 = a22 - 2.0f * w1;
  float na32 = a32 - (uu * w1 + w2);
  float na33 = a33 - 2.0f * (uu * w2);
  d[0] = a11; d[1] = na22; d[2] = na33;
  e[0] = beta; e[1] = na32;
  *tau = taui; *u = uu;
}

// ---------------- K1: kNN via 2x8-bit radix-select (R12 exact code) ----------------
__global__ __launch_bounds__(256) void knn_kernel(const float* __restrict__ pts,
                                                  float* __restrict__ out, int N) {
  __shared__ unsigned skey[NPTS];      // 16 KB
  __shared__ unsigned hist[256];
  __shared__ unsigned sred[4];
  __shared__ unsigned sbin[2];
  __shared__ int   eqi[64];
  __shared__ float eqd[64];
  __shared__ unsigned eqn[1];
  const int i = blockIdx.x;
  const int tid = threadIdx.x;
  const int lane = tid & 63, wid = tid >> 6;
  if (i == 0 && tid == 0) out[0] = 0.0f;        // curv accumulates atomically later
  const float xi = pts[3 * i], yi = pts[3 * i + 1], zi = pts[3 * i + 2];
  const float d2i = xi * xi + yi * yi + zi * zi;
  hist[tid] = 0;
  if (tid == 0) eqn[0] = 0;
  __syncthreads();
  for (int j = tid; j < N; j += 256) {
    float xj = pts[3 * j], yj = pts[3 * j + 1], zj = pts[3 * j + 2];
    float d2j = xj * xj + yj * yj + zj * zj;
    float dot = fmaf(zi, zj, fmaf(yi, yj, xi * xj));
    float dist = (d2i - 2.0f * dot) + d2j;        // identical formula to R1..R15
    float dc = fminf(fmaxf(dist, 0.0f), 31.0f);
    unsigned u = (unsigned)(dc * 134217728.0f);   // *2^27 exact, trunc: monotone
    skey[j] = u;
    atomicAdd(&hist[u >> 24], 1u);                // fused pass-0 histogram
  }
  __syncthreads();
  unsigned prefix = 0, rank = 49;
  for (int pass = 0; pass < 2; ++pass) {
    const int shift = 24 - 8 * pass;
    if (pass) {
      for (int j = tid; j < N; j += 256) {
        unsigned u = skey[j];
        if ((u >> 24) == (prefix >> 24))
          atomicAdd(&hist[(u >> 16) & 255u], 1u);
      }
      __syncthreads();
    }
    unsigned h = hist[tid];
    unsigned c = h;
    #pragma unroll
    for (int off = 1; off < 64; off <<= 1) {
      unsigned o = __shfl_up(c, off);
      if (lane >= off) c += o;
    }
    if (lane == 63) sred[wid] = c;
    __syncthreads();
    unsigned wbase = 0;
    for (int w2 = 0; w2 < wid; ++w2) wbase += sred[w2];
    c += wbase;
    unsigned excl = c - h;
    if (rank >= excl && rank < c) { sbin[0] = (unsigned)tid; sbin[1] = rank - excl; }
    __syncthreads();
    prefix |= sbin[0] << shift;
    rank = sbin[1];
    __syncthreads();
    if (pass == 0) { hist[tid] = 0; __syncthreads(); }
  }
  const unsigned T = prefix;                      // low 16 bits zero
  int cnt = 0;
  for (int j = tid; j < N; j += 256) {
    unsigned u = skey[j];
    if (u < T && j != i) {
      ++cnt;
    } else if ((u & 0xFFFF0000u) == T) {
      float xj = pts[3 * j], yj = pts[3 * j + 1], zj = pts[3 * j + 2];
      float d2j = xj * xj + yj * yj + zj * zj;
      float dot = fmaf(zi, zj, fmaf(yi, yj, xi * xj));
      float dist = (d2i - 2.0f * dot) + d2j;
      unsigned e = atomicAdd(&eqn[0], 1u);
      if (e < 64u) { eqi[e] = j; eqd[e] = dist; }
    }
  }
  __syncthreads();
  unsigned cc = (unsigned)cnt;
  #pragma unroll
  for (int off = 1; off < 64; off <<= 1) {
    unsigned o = __shfl_up(cc, off);
    if (lane >= off) cc += o;
  }
  if (lane == 63) sred[wid] = cc;
  __syncthreads();
  unsigned wbase = 0;
  for (int w2 = 0; w2 < wid; ++w2) wbase += sred[w2];
  int base = 1 + (int)(wbase + cc - (unsigned)cnt);  // deterministic compaction slot
  for (int j = tid; j < N; j += 256) {
    unsigned u = skey[j];
    if (u < T && j != i) g_idx[i * KNB + (base++)] = j;
  }
  if (tid == 0) {
    g_idx[i * KNB] = i;                            // self = global min distance
    int slot = 1 + (int)(sred[0] + sred[1] + sred[2] + sred[3]);
    int need = KNB - slot;                         // >= 1
    int ne = (int)eqn[0]; if (ne > 64) ne = 64;
    for (int e2 = 0; e2 < need; ++e2) {            // exact (dist, index) ascending
      int bq = 0, bidx = 0x7FFFFFFF; float bd = 3.4e38f;
      for (int q = 0; q < ne; ++q) {
        if (eqi[q] < 0) continue;
        float dq = eqd[q];
        if (dq < bd || (dq == bd && eqi[q] < bidx)) { bd = dq; bidx = eqi[q]; bq = q; }
      }
      g_idx[i * KNB + slot + e2] = bidx;
      eqi[bq] = -1;
    }
  }
}

// ---------------- K2: frames, wave-per-point (exact R2 accumulation order) ---------
__global__ __launch_bounds__(256) void frames_kernel(const float* __restrict__ pts, int N) {
  __shared__ float sx[4][52], sy[4][52], sz[4][52];
  const int tid = threadIdx.x, lane = tid & 63, w = tid >> 6;
  const int i = blockIdx.x * 4 + w;
  const int base = i * KNB;
  if (lane < KNB) {
    int j = g_idx[base + lane];
    sx[w][lane] = pts[3 * j];
    sy[w][lane] = pts[3 * j + 1];
    sz[w][lane] = pts[3 * j + 2];
  }
  __syncthreads();
  float mx = 0.0f, my = 0.0f, mz = 0.0f;
  for (int kk = 0; kk < KNB; ++kk) { mx += sx[w][kk]; my += sy[w][kk]; mz += sz[w][kk]; }
  mx /= 50.0f; my /= 50.0f; mz /= 50.0f;
  float c00 = 0, c01 = 0, c02 = 0, c11 = 0, c12 = 0, c22 = 0;
  for (int kk = 0; kk < KNB; ++kk) {
    float cx = sx[w][kk] - mx, cy = sy[w][kk] - my, cz = sz[w][kk] - mz;
    c00 = fmaf(cx, cx, c00); c01 = fmaf(cx, cy, c01); c02 = fmaf(cx, cz, c02);
    c11 = fmaf(cy, cy, c11); c12 = fmaf(cy, cz, c12); c22 = fmaf(cz, cz, c22);
  }
  c00 *= 0.5f; c01 *= 0.5f; c02 *= 0.5f; c11 *= 0.5f; c12 *= 0.5f; c22 *= 0.5f;

  float d[3], e[2], tau, u;
  ssytrd3(c00, c01, c02, c11, c12, c22, d, e, &tau, &u);
  float Z[3][3];
  ssteqr3(d, e, Z);
  if (tau != 0.0f) {
    for (int c = 0; c < 3; ++c) {
      float sum = Z[1][c] + u * Z[2][c];
      Z[1][c] -= tau * sum;
      Z[2][c] -= tau * u * sum;
    }
  }
  float n0 = Z[0][0], n1 = Z[1][0], n2 = Z[2][0];
  float a0 = Z[0][1], a1 = Z[1][1], a2 = Z[2][1];
  float b0 = Z[0][2], b1 = Z[1][2], b2 = Z[2][2];
  float cxp = a1 * b2 - a2 * b1, cyp = a2 * b0 - a0 * b2, czp = a0 * b1 - a1 * b0;
  float det = n0 * cxp + n1 * cyp + n2 * czp;
  a0 *= det; a1 *= det; a2 *= det;

  const float xi = pts[3 * i], yi = pts[3 * i + 1], zi = pts[3 * i + 2];
  float dt0 = 0.0f, dt1 = 0.0f;
  float mn0 = 3.0e38f, mx0 = -3.0e38f, mn1 = 3.0e38f, mx1 = -3.0e38f;
  if (lane < KNB) {
    float dx = sx[w][lane] - xi, dy = sy[w][lane] - yi, dz = sz[w][lane] - zi;
    dt0 = dx * a0 + dy * a1 + dz * a2;
    dt1 = dx * b0 + dy * b1 + dz * b2;
    g_dt[2 * (base + lane)] = dt0;
    g_dt[2 * (base + lane) + 1] = dt1;
    mn0 = dt0; mx0 = dt0; mn1 = dt1; mx1 = dt1;
  }
  #pragma unroll
  for (int off = 32; off > 0; off >>= 1) {
    mn0 = fminf(mn0, __shfl_down(mn0, off));
    mx0 = fmaxf(mx0, __shfl_down(mx0, off));
    mn1 = fminf(mn1, __shfl_down(mn1, off));
    mx1 = fmaxf(mx1, __shfl_down(mx1, off));
  }
  if (lane == 0) {
    g_nrm[3 * i] = n0; g_nrm[3 * i + 1] = n1; g_nrm[3 * i + 2] = n2;
    g_t1[3 * i] = a0;  g_t1[3 * i + 1] = a1;  g_t1[3 * i + 2] = a2;
    g_t2[3 * i] = b0;  g_t2[3 * i + 1] = b1;  g_t2[3 * i + 2] = b2;
    float bmin0 = mn0 * 1.1f, bmax0 = mx0 * 1.1f;
    float bmin1 = mn1 * 1.1f, bmax1 = mx1 * 1.1f;
    float ml = fmaxf(bmax0 - bmin0, bmax1 - bmin1);
    g_bmin[2 * i] = bmin0; g_bmin[2 * i + 1] = bmin1;
    g_ml[i] = ml;
  }
}

// ---------------- K3: Voronoi — exact linear block pruning (R12 exact code) --------
__global__ __launch_bounds__(256, 8) void voronoi_kernel(int N) {
  __shared__ float2 sc[KNB];
  __shared__ int alist[64];
  __shared__ int acnt[1];
  __shared__ int swc[4];
  const int i = blockIdx.x;
  const int tid = threadIdx.x;
  const int lane = tid & 63, wid = tid >> 6;   // 4 waves
  const float ml = g_ml[i];
  const float b0 = g_bmin[2 * i], b1 = g_bmin[2 * i + 1];
  if (tid < KNB) {
    float dt0 = g_dt[2 * (i * KNB + tid)];
    float dt1 = g_dt[2 * (i * KNB + tid) + 1];
    sc[tid] = make_float2((dt0 - b0) / ml * 2.0f - 1.0f,
                          (dt1 - b1) / ml * 2.0f - 1.0f);
  }
  if (tid == 0) acnt[0] = 0;
  __syncthreads();
  const float step = 2.0f / 63.0f;
  if (tid < 64) {
    const int bx = tid & 7, by = tid >> 3;
    const float gx0 = fmaf((float)(bx * 8), step, -1.0f);
    const float gx1 = fmaf((float)(bx * 8 + 7), step, -1.0f);
    const float gy0 = fmaf((float)(by * 8), step, -1.0f);
    const float gy1 = fmaf((float)(by * 8 + 7), step, -1.0f);
    const float s0x = sc[0].x, s0y = sc[0].y;
    const float n0s = s0x * s0x + s0y * s0y;
    bool dead = false;
    #pragma clang loop unroll(disable)
    for (int j = 1; j < KNB && !dead; ++j) {
      float sx = sc[j].x, sy = sc[j].y;
      float ax2 = 2.0f * (sx - s0x), ay2 = 2.0f * (sy - s0y);
      float cst = n0s - (sx * sx + sy * sy);
      float Lmin = fminf(ax2 * gx0, ax2 * gx1) + fminf(ay2 * gy0, ay2 * gy1) + cst;
      dead = Lmin > 1e-4f;
    }
    if (!dead) { int p = atomicAdd(&acnt[0], 1); alist[p] = tid; }
  }
  __syncthreads();
  const int na = acnt[0];
  const float c0x = sc[0].x, c0y = sc[0].y;
  int cnt = 0;
  #pragma clang loop unroll(disable)
  for (int k = wid; k < na; k += 4) {
    int b = alist[k];
    int ix = (b & 7) * 8 + (lane & 7);
    int iy = (b >> 3) * 8 + (lane >> 3);
    float gx = fmaf((float)ix, step, -1.0f);
    float gy = fmaf((float)iy, step, -1.0f);
    float ex = gx - c0x, ey = gy - c0y;
    float d0 = ex * ex + ey * ey;
    float m = 3.0e38f;
    #pragma clang loop unroll(disable)
    for (int j = 1; j < KNB; ++j) {
      float dx = gx - sc[j].x, dy = gy - sc[j].y;
      float dd = fmaf(dx, dx, dy * dy);
      m = fminf(m, dd);
    }
    cnt += (d0 <= m) ? 1 : 0;
  }
  #pragma unroll
  for (int off = 32; off > 0; off >>= 1) cnt += __shfl_down(cnt, off);
  if (lane == 0) swc[wid] = cnt;
  __syncthreads();
  if (tid == 0) {
    int tot = swc[0] + swc[1] + swc[2] + swc[3];
    g_va[i] = (float)tot * (ml * ml) / 3969.0f;
  }
}

// ---------------- K4: Weingarten fit + atomic global sum (R12 exact code) ----------
__global__ __launch_bounds__(256) void curv_kernel(float* __restrict__ out, int N) {
  __shared__ float s0[4][52], s1[4][52], tx[4][52], ty[4][52], tz[4][52];
  __shared__ float bsum[4];
  const int tid = threadIdx.x, lane = tid & 63, w = tid >> 6;
  const int i = blockIdx.x * 4 + w;
  const int base = i * KNB;
  if (lane < KNB) {
    int j = g_idx[base + lane];
    s0[w][lane] = g_dt[2 * (base + lane)];
    s1[w][lane] = g_dt[2 * (base + lane) + 1];
    tx[w][lane] = g_nrm[3 * j];
    ty[w][lane] = g_nrm[3 * j + 1];
    tz[w][lane] = g_nrm[3 * j + 2];
  }
  __syncthreads();
  float nx = g_nrm[3 * i], ny = g_nrm[3 * i + 1], nz = g_nrm[3 * i + 2];
  float ax = g_t1[3 * i], ay = g_t1[3 * i + 1], az = g_t1[3 * i + 2];
  float bx = g_t2[3 * i], by = g_t2[3 * i + 1], bz = g_t2[3 * i + 2];
  float xx = 0, xy = 0, yy = 0;
  float y00 = 0, y01 = 0, y10 = 0, y11 = 0;
  for (int kk = 0; kk < KNB; ++kk) {
    float dt0 = s0[w][kk], dt1 = s1[w][kk];
    float lx = tx[w][kk] - nx, ly = ty[w][kk] - ny, lz = tz[w][kk] - nz;
    float dn0 = lx * ax + ly * ay + lz * az;
    float dn1 = lx * bx + ly * by + lz * bz;
    xx = fmaf(dt0, dt0, xx); xy = fmaf(dt0, dt1, xy); yy = fmaf(dt1, dt1, yy);
    y00 = fmaf(dn0, dt0, y00); y01 = fmaf(dn0, dt1, y01);
    y10 = fmaf(dn1, dt0, y10); y11 = fmaf(dn1, dt1, y11);
  }
  float s00 = y00 + y00, s01 = y01 + y10, s11 = y11 + y11;
  float rt1, rt2, cs1, sn1;
  slaev2f(xx, xy, yy, &rt1, &rt2, &cs1, &sn1);
  float a, bb, q00, q10, q01, q11;
  if (rt1 <= rt2) { a = rt1; bb = rt2; q00 = cs1; q10 = sn1; q01 = -sn1; q11 = cs1; }
  else            { a = rt2; bb = rt1; q00 = -sn1; q10 = cs1; q01 = cs1; q11 = sn1; }
  float t00 = s00 * q00 + s01 * q10, t01 = s00 * q01 + s01 * q11;
  float t10 = s01 * q00 + s11 * q10, t11 = s01 * q01 + s11 * q11;
  float m00 = q00 * t00 + q10 * t10;
  float m01 = q00 * t01 + q10 * t11;
  float m10 = q01 * t00 + q11 * t10;
  float m11 = q01 * t01 + q11 * t11;
  float e00 = m00 / (2.0f * a + 1e-8f);
  float e01 = m01 / ((a + bb) + 1e-8f);
  float e10 = m10 / ((a + bb) + 1e-8f);
  float e11 = m11 / (2.0f * bb + 1e-8f);
  float u00 = q00 * e00 + q01 * e10, u01 = q00 * e01 + q01 * e11;
  float u10 = q10 * e00 + q11 * e10, u11 = q10 * e01 + q11 * e11;
  float w00 = u00 * q00 + u01 * q01;
  float w01 = u00 * q10 + u01 * q11;
  float w10 = u10 * q00 + u11 * q01;
  float w11 = u10 * q10 + u11 * q11;
  float gauss = w00 * w11 - w01 * w10;
  if (lane == 0) bsum[w] = gauss * g_va[i] * 0.15915494309189535f;  // /(2*pi)
  __syncthreads();
  if (tid == 0)
    atomicAdd(out, bsum[0] + bsum[1] + bsum[2] + bsum[3]);  // one atomic per block
}

extern "C" void kernel_launch(void* const* d_in, const int* in_sizes, int n_in,
                              void* d_out, int out_size, void* d_ws, size_t ws_size,
                              hipStream_t stream) {
  const float* pts = (const float*)d_in[0];
  float* out = (float*)d_out;
  const int N = in_sizes[0] / 3;   // 4096
  knn_kernel<<<N, 256, 0, stream>>>(pts, out, N);
  frames_kernel<<<N / 4, 256, 0, stream>>>(pts, N);
  voronoi_kernel<<<N, 256, 0, stream>>>(N);
  curv_kernel<<<N / 4, 256, 0, stream>>>(out, N);
}